// Round 7
// baseline (334.509 us; speedup 1.0000x reference)
//
#include <hip/hip_runtime.h>
#include <math.h>

// Problem constants (B=4, S=1024, E=512, H=8, D=64, T_MAX=20)
#define SEQ   1024
#define EMB   512
#define NROWS 4096   // B*S
#define LDP   72     // attn LDS row stride (bf16 elems)
#define GROWS 8      // gates rows per block

typedef __attribute__((ext_vector_type(8))) short short8;    // bf16 x8 MFMA frag
typedef __attribute__((ext_vector_type(4))) float float4v;   // f32 x4 MFMA acc

__device__ __forceinline__ float bf2f(unsigned short s) {
    union { float f; unsigned u; } x; x.u = ((unsigned)s) << 16; return x.f;
}
__device__ __forceinline__ unsigned short f2bf(float f) {
    union { float f; unsigned u; } x; x.f = f;
    unsigned r = x.u + 0x7fffu + ((x.u >> 16) & 1u);   // round-to-nearest-even
    return (unsigned short)(r >> 16);
}

// ---------------------------------------------------------------------------
// K0: gate + complexity MLPs -> T_i[4096]. 8 rows per block (256 threads).
// All-f32 (R6 showed ref is f32-grade; our-vs-ref score noise is the ref's
// own ~1e-7 either way, so f64 bought nothing). Same structure as R4/R6.
// ---------------------------------------------------------------------------
template<int H1, int H2>
__device__ __forceinline__ float gate_mlp_block(
    const float xs[GROWS][EMB], float h1[GROWS][128], float h2[GROWS][64],
    float* mu_s, float* var_s,
    const float* __restrict__ W1, const float* __restrict__ b1,
    const float* __restrict__ gam, const float* __restrict__ bet,
    const float* __restrict__ W2, const float* __restrict__ b2,
    const float* __restrict__ W3, const float* __restrict__ b3,
    int tid, int myrow)
{
    constexpr int RN1 = GROWS * H1 / 256;
    constexpr int RN2 = GROWS * H2 / 256;

    {   // h1 = x @ W1 + b1
        const int col = tid % H1;
        const int rb  = (tid / H1) * RN1;
        float acc[RN1];
        #pragma unroll
        for (int r = 0; r < RN1; ++r) acc[r] = b1[col];
        for (int k = 0; k < EMB; ++k) {
            const float w = W1[k * H1 + col];
            #pragma unroll
            for (int r = 0; r < RN1; ++r) acc[r] += w * xs[rb + r][k];
        }
        #pragma unroll
        for (int r = 0; r < RN1; ++r) h1[rb + r][col] = acc[r];
    }
    __syncthreads();

    {   // mean
        const int r = tid >> 5, l = tid & 31;
        float s = 0.f;
        for (int c = l; c < H1; c += 32) s += h1[r][c];
        #pragma unroll
        for (int off = 16; off >= 1; off >>= 1) s += __shfl_xor(s, off);
        if (l == 0) mu_s[r] = s / (float)H1;
    }
    __syncthreads();
    {   // var
        const int r = tid >> 5, l = tid & 31;
        const float mu = mu_s[r];
        float s = 0.f;
        for (int c = l; c < H1; c += 32) { const float d = h1[r][c] - mu; s += d * d; }
        #pragma unroll
        for (int off = 16; off >= 1; off >>= 1) s += __shfl_xor(s, off);
        if (l == 0) var_s[r] = s / (float)H1;
    }
    __syncthreads();
    // normalize + relu
    for (int idx = tid; idx < GROWS * H1; idx += 256) {
        const int r = idx / H1, cc = idx % H1;
        float hn = (h1[r][cc] - mu_s[r]) / sqrtf(var_s[r] + 1e-5f) * gam[cc] + bet[cc];
        h1[r][cc] = hn > 0.f ? hn : 0.f;
    }
    __syncthreads();

    {   // h2 = relu(h1 @ W2 + b2)
        const int col = tid % H2;
        const int rb  = (tid / H2) * RN2;
        float acc[RN2];
        #pragma unroll
        for (int r = 0; r < RN2; ++r) acc[r] = b2[col];
        for (int k = 0; k < H1; ++k) {
            const float w = W2[k * H2 + col];
            #pragma unroll
            for (int r = 0; r < RN2; ++r) acc[r] += w * h1[rb + r][k];
        }
        #pragma unroll
        for (int r = 0; r < RN2; ++r) h2[rb + r][col] = acc[r] > 0.f ? acc[r] : 0.f;
    }
    __syncthreads();

    {   // scalar = h2 @ W3 (sigmoid below)
        const int r = tid >> 5, l = tid & 31;
        float s = 0.f;
        for (int c = l; c < H2; c += 32) s += h2[r][c] * W3[c];
        #pragma unroll
        for (int off = 16; off >= 1; off >>= 1) s += __shfl_xor(s, off);
        if (l == 0) mu_s[r] = s;   // reuse as scratch
    }
    __syncthreads();
    float ret = 0.f;
    if (myrow >= 0) {
        const float z = mu_s[myrow] + b3[0];
        ret = 1.0f / (1.0f + expf(-z));
    }
    __syncthreads();
    return ret;
}

__global__ __launch_bounds__(256) void gates_kernel(
    const float* __restrict__ x,
    const float* __restrict__ gW1, const float* __restrict__ gb1,
    const float* __restrict__ gg,  const float* __restrict__ gbe,
    const float* __restrict__ gW2, const float* __restrict__ gb2,
    const float* __restrict__ gW3, const float* __restrict__ gb3,
    const float* __restrict__ cW1, const float* __restrict__ cb1,
    const float* __restrict__ cg,  const float* __restrict__ cbe,
    const float* __restrict__ cW2, const float* __restrict__ cb2,
    const float* __restrict__ cW3, const float* __restrict__ cb3,
    int* __restrict__ T_i)
{
    __shared__ float xs[GROWS][EMB];     // 16 KB
    __shared__ float h1[GROWS][128];     // 4 KB
    __shared__ float h2[GROWS][64];      // 2 KB
    __shared__ float mu_s[GROWS], var_s[GROWS];

    const int row0 = blockIdx.x * GROWS;
    const int tid = threadIdx.x;

    for (int idx = tid; idx < GROWS * EMB; idx += 256) {
        const int r = idx >> 9, cc = idx & 511;
        xs[r][cc] = x[(size_t)(row0 + r) * EMB + cc];
    }
    __syncthreads();

    const int myrow = (tid < GROWS) ? tid : -1;
    const float g0 = gate_mlp_block<128, 64>(xs, h1, h2, mu_s, var_s,
                                             gW1, gb1, gg, gbe, gW2, gb2, gW3, gb3, tid, myrow);
    const float c0 = gate_mlp_block<64, 32>(xs, h1, h2, mu_s, var_s,
                                            cW1, cb1, cg, cbe, cW2, cb2, cW3, cb3, tid, myrow);

    if (tid < GROWS) {
        const int row = row0 + tid;
        const int s = row & (SEQ - 1);
        const float step = (1.2f - 0.8f) / (float)(SEQ - 1);   // np.linspace step
        const float pos  = (float)s * step + 0.8f;
        const float score = ((1.0f - 0.3f) * g0 + 0.3f * c0) * pos;
        float t = ceilf(score * 20.0f);
        t = t < 1.f ? 1.f : (t > 20.f ? 20.f : t);
        T_i[row] = (int)t;
    }
}

// ---------------------------------------------------------------------------
// K1: QKV GEMM f32 VALU, BK=32 (half the barriers of R6), 128x64 tile,
// A staged transposed (Ast[k][m]) so per-kk reads are broadcast ds_read_b128.
// LIF epilogue in f32 with np-exact separate rounding (__fmul_rn/__fadd_rn).
// ---------------------------------------------------------------------------
__global__ __launch_bounds__(256) void qkv_lif_kernel(
    const float* __restrict__ x,
    const float* __restrict__ Wq, const float* __restrict__ Wk, const float* __restrict__ Wv,
    const float* __restrict__ aq, const float* __restrict__ bq,
    const float* __restrict__ akp, const float* __restrict__ bkp,
    const float* __restrict__ av, const float* __restrict__ bv,
    const int* __restrict__ T_i,
    unsigned short* __restrict__ q_sum, unsigned short* __restrict__ k_sum,
    unsigned short* __restrict__ v_mean)
{
    const int z = blockIdx.z;
    const float* __restrict__ W = (z == 0) ? Wq : (z == 1) ? Wk : Wv;
    unsigned short* __restrict__ out = (z == 0) ? q_sum : (z == 1) ? k_sum : v_mean;
    const float alpha = ((z == 0) ? aq : (z == 1) ? akp : av)[0];
    const float beta  = ((z == 0) ? bq : (z == 1) ? bkp : bv)[0];

    __shared__ __align__(16) float Ast[32][132];  // [k][m], 16.9 KB
    __shared__ __align__(16) float Bs[32][68];    // [k][n], 8.7 KB

    const int tid = threadIdx.x;
    const int tx = tid & 15, ty = tid >> 4;
    const int row0 = blockIdx.y * 128, col0 = blockIdx.x * 64;

    float4 acc0[8];   // acc0[i].{x,y,z,w} = cols 0..3 of row i
    #pragma unroll
    for (int i = 0; i < 8; ++i) acc0[i] = (float4){0.f, 0.f, 0.f, 0.f};

    for (int k0 = 0; k0 < EMB; k0 += 32) {
        // A: 128 rows x 32 k = 1024 float4, 4 per thread, scatter-transpose
        #pragma unroll
        for (int it = 0; it < 4; ++it) {
            const int f = it * 256 + tid;
            const int ar = f >> 3, ac4 = (f & 7) * 4;
            const float4 a4 = *(const float4*)&x[(size_t)(row0 + ar) * EMB + k0 + ac4];
            Ast[ac4 + 0][ar] = a4.x; Ast[ac4 + 1][ar] = a4.y;
            Ast[ac4 + 2][ar] = a4.z; Ast[ac4 + 3][ar] = a4.w;
        }
        // B: 32 rows x 64 n = 512 float4, 2 per thread, vector stores
        #pragma unroll
        for (int it = 0; it < 2; ++it) {
            const int f = it * 256 + tid;
            const int br = f >> 4, bc4 = (f & 15) * 4;
            const float4 b4 = *(const float4*)&W[(size_t)(k0 + br) * EMB + col0 + bc4];
            *(float4*)&Bs[br][bc4] = b4;
        }
        __syncthreads();
        #pragma unroll
        for (int kk = 0; kk < 32; ++kk) {
            const float4 a0 = *(const float4*)&Ast[kk][ty * 8];
            const float4 a1 = *(const float4*)&Ast[kk][ty * 8 + 4];
            const float4 bb = *(const float4*)&Bs[kk][tx * 4];
            acc0[0].x += a0.x * bb.x; acc0[0].y += a0.x * bb.y; acc0[0].z += a0.x * bb.z; acc0[0].w += a0.x * bb.w;
            acc0[1].x += a0.y * bb.x; acc0[1].y += a0.y * bb.y; acc0[1].z += a0.y * bb.z; acc0[1].w += a0.y * bb.w;
            acc0[2].x += a0.z * bb.x; acc0[2].y += a0.z * bb.y; acc0[2].z += a0.z * bb.z; acc0[2].w += a0.z * bb.w;
            acc0[3].x += a0.w * bb.x; acc0[3].y += a0.w * bb.y; acc0[3].z += a0.w * bb.z; acc0[3].w += a0.w * bb.w;
            acc0[4].x += a1.x * bb.x; acc0[4].y += a1.x * bb.y; acc0[4].z += a1.x * bb.z; acc0[4].w += a1.x * bb.w;
            acc0[5].x += a1.y * bb.x; acc0[5].y += a1.y * bb.y; acc0[5].z += a1.y * bb.z; acc0[5].w += a1.y * bb.w;
            acc0[6].x += a1.z * bb.x; acc0[6].y += a1.z * bb.y; acc0[6].z += a1.z * bb.z; acc0[6].w += a1.z * bb.w;
            acc0[7].x += a1.w * bb.x; acc0[7].y += a1.w * bb.y; acc0[7].z += a1.w * bb.z; acc0[7].w += a1.w * bb.w;
        }
        __syncthreads();
    }

    // LIF epilogue: f32, np-exact op order (separate mul/add roundings)
    #pragma unroll
    for (int i = 0; i < 8; ++i) {
        const int gm = row0 + ty * 8 + i;
        const int T = T_i[gm];
        const float vals[4] = {acc0[i].x, acc0[i].y, acc0[i].z, acc0[i].w};
        ushort4 pack;
        unsigned short* pk = (unsigned short*)&pack;
        #pragma unroll
        for (int j = 0; j < 4; ++j) {
            const float xv = vals[j];
            float cur = 0.f, vm = 0.f, spikes = 0.f;
            for (int t = 0; t < T; ++t) {
                cur = __fadd_rn(__fmul_rn(alpha, cur), xv);
                vm  = __fadd_rn(__fmul_rn(beta, vm), cur);
                if (vm >= 1.0f) { spikes += 1.0f; vm = 0.f; }
            }
            if (z == 2) spikes = spikes / 20.0f;
            pk[j] = f2bf(spikes);
        }
        *(ushort4*)&out[(size_t)gm * EMB + col0 + tx * 4] = pack;
    }
}

// ---------------------------------------------------------------------------
// K2: fused flash-style MFMA attention; epilogue emits bf16. (R6-identical)
// ---------------------------------------------------------------------------
__global__ __launch_bounds__(256) void attn_mfma_kernel(
    const unsigned short* __restrict__ q, const unsigned short* __restrict__ k,
    const unsigned short* __restrict__ v, unsigned short* __restrict__ attn_bf)
{
    __shared__ __align__(16) short Ks[64 * LDP];
    __shared__ __align__(16) short Pt[64 * LDP];
    __shared__ __align__(16) short Vt[64 * LDP];

    const int b = blockIdx.z, h = blockIdx.y;
    const int i0 = blockIdx.x * 64;
    const int tid  = threadIdx.x;
    const int wave = tid >> 6, lane = tid & 63;
    const int quad = lane >> 4, c = lane & 15;

    const unsigned short* Qb = q + ((size_t)b * SEQ + i0) * EMB + h * 64;
    const unsigned short* Kb = k + (size_t)b * SEQ * EMB + h * 64;
    const unsigned short* Vb = v + (size_t)b * SEQ * EMB + h * 64;

    short8 qf[2];
    {
        const int qrow = wave * 16 + c;
        #pragma unroll
        for (int ks = 0; ks < 2; ++ks) {
            short8 raw = *(const short8*)(Qb + (size_t)qrow * EMB + ks * 32 + quad * 8);
            short8 sc8;
            #pragma unroll
            for (int j = 0; j < 8; ++j)
                sc8[j] = (short)f2bf(bf2f((unsigned short)raw[j]) * 0.125f);
            qf[ks] = sc8;
        }
    }

    float m_r[4], l_r[4];
    float4v o[4];
    #pragma unroll
    for (int r = 0; r < 4; ++r) { m_r[r] = -1e30f; l_r[r] = 0.f; }
    #pragma unroll
    for (int nb = 0; nb < 4; ++nb)
        #pragma unroll
        for (int r = 0; r < 4; ++r) o[nb][r] = 0.f;

    for (int jt = 0; jt < SEQ / 64; ++jt) {
        #pragma unroll
        for (int it = 0; it < 2; ++it) {
            const int idx = it * 256 + tid;
            const int row = idx >> 3, ch = idx & 7;
            short8 val = *(const short8*)(Kb + (size_t)(jt * 64 + row) * EMB + ch * 8);
            *(short8*)&Ks[row * LDP + ch * 8] = val;
        }
        __syncthreads();

        float sc[4][4];
        #pragma unroll
        for (int nb = 0; nb < 4; ++nb) {
            float4v acc = {0.f, 0.f, 0.f, 0.f};
            #pragma unroll
            for (int ks = 0; ks < 2; ++ks) {
                short8 bfrag = *(const short8*)&Ks[(nb * 16 + c) * LDP + ks * 32 + quad * 8];
                acc = __builtin_amdgcn_mfma_f32_16x16x32_bf16(qf[ks], bfrag, acc, 0, 0, 0);
            }
            #pragma unroll
            for (int r = 0; r < 4; ++r) sc[nb][r] = acc[r];
        }

        float mnew[4], alpha[4];
        #pragma unroll
        for (int r = 0; r < 4; ++r) {
            float mx = fmaxf(fmaxf(sc[0][r], sc[1][r]), fmaxf(sc[2][r], sc[3][r]));
            #pragma unroll
            for (int off = 8; off >= 1; off >>= 1) mx = fmaxf(mx, __shfl_xor(mx, off));
            mnew[r]  = fmaxf(m_r[r], mx);
            alpha[r] = __expf(m_r[r] - mnew[r]);
            m_r[r]   = mnew[r];
        }
        float psum[4] = {0.f, 0.f, 0.f, 0.f};
        #pragma unroll
        for (int nb = 0; nb < 4; ++nb)
            #pragma unroll
            for (int r = 0; r < 4; ++r) {
                float p = __expf(sc[nb][r] - mnew[r]);
                psum[r] += p;
                Pt[(wave * 16 + quad * 4 + r) * LDP + nb * 16 + c] = (short)f2bf(p);
            }
        #pragma unroll
        for (int r = 0; r < 4; ++r) {
            float s = psum[r];
            #pragma unroll
            for (int off = 8; off >= 1; off >>= 1) s += __shfl_xor(s, off);
            l_r[r] = l_r[r] * alpha[r] + s;
            #pragma unroll
            for (int nb = 0; nb < 4; ++nb) o[nb][r] *= alpha[r];
        }

        {
            const int m = tid & 7, rp = tid >> 3;
            const int r = rp * 2;
            short8 v0 = *(const short8*)(Vb + (size_t)(jt * 64 + r) * EMB + m * 8);
            short8 v1 = *(const short8*)(Vb + (size_t)(jt * 64 + r + 1) * EMB + m * 8);
            const int rch = r >> 3, rlow = r & 7;
            #pragma unroll
            for (int i = 0; i < 8; ++i) {
                const int d = m * 8 + i;
                const int col = ((rch ^ m) << 3) + rlow;
                *(int*)&Vt[d * LDP + col] =
                    (int)((unsigned)(unsigned short)v0[i] |
                          ((unsigned)(unsigned short)v1[i] << 16));
            }
        }
        __syncthreads();

        short8 pf[2];
        #pragma unroll
        for (int ks = 0; ks < 2; ++ks)
            pf[ks] = *(const short8*)&Pt[(wave * 16 + c) * LDP + ks * 32 + quad * 8];
        #pragma unroll
        for (int nb = 0; nb < 4; ++nb) {
            float4v acc = o[nb];
            #pragma unroll
            for (int ks = 0; ks < 2; ++ks) {
                const int d = nb * 16 + c;
                const int kch = ks * 4 + quad;
                const int col = ((kch ^ (d >> 3)) << 3);
                short8 vfrag = *(const short8*)&Vt[d * LDP + col];
                acc = __builtin_amdgcn_mfma_f32_16x16x32_bf16(pf[ks], vfrag, acc, 0, 0, 0);
            }
            o[nb] = acc;
        }
    }

    #pragma unroll
    for (int r = 0; r < 4; ++r) {
        const float inv = 1.0f / l_r[r];
        const int row = i0 + wave * 16 + quad * 4 + r;
        #pragma unroll
        for (int nb = 0; nb < 4; ++nb)
            attn_bf[((size_t)b * SEQ + row) * EMB + h * 64 + nb * 16 + c] =
                f2bf(o[nb][r] * inv);
    }
}

// ---------------------------------------------------------------------------
// K3a: Wo^T bf16 prep (64x64 LDS transpose tiles). (R6-identical)
// ---------------------------------------------------------------------------
__global__ __launch_bounds__(256) void wot_prep(
    const float* __restrict__ Wo, unsigned short* __restrict__ BT)
{
    __shared__ unsigned short Ws[64][72];
    const int k0 = blockIdx.y * 64, n0 = blockIdx.x * 64;
    const int t = threadIdx.x;
    #pragma unroll
    for (int it = 0; it < 4; ++it) {
        const int idx = it * 256 + t;
        const int r = idx >> 4, c4 = (idx & 15) * 4;
        const float4 w4 = *(const float4*)&Wo[(size_t)(k0 + r) * EMB + n0 + c4];
        Ws[r][c4 + 0] = f2bf(w4.x); Ws[r][c4 + 1] = f2bf(w4.y);
        Ws[r][c4 + 2] = f2bf(w4.z); Ws[r][c4 + 3] = f2bf(w4.w);
    }
    __syncthreads();
    #pragma unroll
    for (int it = 0; it < 2; ++it) {
        const int idx = it * 256 + t;
        const int n = idx >> 3, k8 = (idx & 7) * 8;
        short8 pack;
        #pragma unroll
        for (int j = 0; j < 8; ++j) pack[j] = (short)Ws[k8 + j][n];
        *(short8*)&BT[(size_t)(n0 + n) * EMB + k0 + k8] = pack;
    }
}

// ---------------------------------------------------------------------------
// K3b: out = attn_bf @ Wo + bo via bf16 MFMA, frags direct from global (L2).
// (R6-identical)
// ---------------------------------------------------------------------------
__global__ __launch_bounds__(256) void out_gemm_kernel(
    const unsigned short* __restrict__ A,   // [4096][512] bf16
    const unsigned short* __restrict__ BT,  // [512][512] bf16, [n][k]
    const float* __restrict__ bias, float* __restrict__ out)
{
    const int tid  = threadIdx.x;
    const int lane = tid & 63, wave = tid >> 6;
    const int qd = lane >> 4, c = lane & 15;
    const int wm = (wave & 1) * 32, wn = (wave >> 1) * 32;
    const int row0 = blockIdx.y * 64, col0 = blockIdx.x * 64;

    float4v acc[2][2];
    #pragma unroll
    for (int i = 0; i < 2; ++i)
        #pragma unroll
        for (int j = 0; j < 2; ++j)
            acc[i][j] = (float4v){0.f, 0.f, 0.f, 0.f};

    for (int k0 = 0; k0 < EMB; k0 += 32) {
        short8 af[2], bf[2];
        #pragma unroll
        for (int i = 0; i < 2; ++i)
            af[i] = *(const short8*)&A[(size_t)(row0 + wm + i * 16 + c) * EMB + k0 + qd * 8];
        #pragma unroll
        for (int j = 0; j < 2; ++j)
            bf[j] = *(const short8*)&BT[(size_t)(col0 + wn + j * 16 + c) * EMB + k0 + qd * 8];
        #pragma unroll
        for (int i = 0; i < 2; ++i)
            #pragma unroll
            for (int j = 0; j < 2; ++j)
                acc[i][j] = __builtin_amdgcn_mfma_f32_16x16x32_bf16(af[i], bf[j], acc[i][j], 0, 0, 0);
    }

    #pragma unroll
    for (int i = 0; i < 2; ++i)
        #pragma unroll
        for (int r = 0; r < 4; ++r) {
            const int gm = row0 + wm + i * 16 + qd * 4 + r;
            #pragma unroll
            for (int j = 0; j < 2; ++j) {
                const int gn = col0 + wn + j * 16 + c;
                out[(size_t)gm * EMB + gn] = acc[i][j][r] + bias[gn];
            }
        }
}

// ---------------------------------------------------------------------------
extern "C" void kernel_launch(void* const* d_in, const int* in_sizes, int n_in,
                              void* d_out, int out_size, void* d_ws, size_t ws_size,
                              hipStream_t stream)
{
    const float* x   = (const float*)d_in[0];
    const float* Wq  = (const float*)d_in[1];
    const float* Wk  = (const float*)d_in[2];
    const float* Wv  = (const float*)d_in[3];
    const float* Wo  = (const float*)d_in[4];
    const float* bo  = (const float*)d_in[5];
    const float* gW1 = (const float*)d_in[6];
    const float* gb1 = (const float*)d_in[7];
    const float* gg  = (const float*)d_in[8];
    const float* gbe = (const float*)d_in[9];
    const float* gW2 = (const float*)d_in[10];
    const float* gb2 = (const float*)d_in[11];
    const float* gW3 = (const float*)d_in[12];
    const float* gb3 = (const float*)d_in[13];
    const float* cW1 = (const float*)d_in[14];
    const float* cb1 = (const float*)d_in[15];
    const float* cg  = (const float*)d_in[16];
    const float* cbe = (const float*)d_in[17];
    const float* cW2 = (const float*)d_in[18];
    const float* cb2 = (const float*)d_in[19];
    const float* cW3 = (const float*)d_in[20];
    const float* cb3 = (const float*)d_in[21];
    const float* aq  = (const float*)d_in[22];
    const float* bq  = (const float*)d_in[23];
    const float* ak  = (const float*)d_in[24];
    const float* bk  = (const float*)d_in[25];
    const float* av  = (const float*)d_in[26];
    const float* bv  = (const float*)d_in[27];

    int* Tp = (int*)d_ws;
    unsigned short* q_sum   = (unsigned short*)((char*)d_ws + 16384);
    unsigned short* k_sum   = q_sum   + (size_t)NROWS * EMB;
    unsigned short* v_mean  = k_sum   + (size_t)NROWS * EMB;
    unsigned short* attn_bf = v_mean  + (size_t)NROWS * EMB;
    unsigned short* WoT     = attn_bf + (size_t)NROWS * EMB;
    float* out = (float*)d_out;

    gates_kernel<<<dim3(NROWS / GROWS), dim3(256), 0, stream>>>(
        x, gW1, gb1, gg, gbe, gW2, gb2, gW3, gb3,
        cW1, cb1, cg, cbe, cW2, cb2, cW3, cb3, Tp);

    qkv_lif_kernel<<<dim3(EMB / 64, NROWS / 128, 3), dim3(256), 0, stream>>>(
        x, Wq, Wk, Wv, aq, bq, ak, bk, av, bv, Tp, q_sum, k_sum, v_mean);

    wot_prep<<<dim3(EMB / 64, EMB / 64), dim3(256), 0, stream>>>(Wo, WoT);

    attn_mfma_kernel<<<dim3(SEQ / 64, 8, 4), dim3(256), 0, stream>>>(
        q_sum, k_sum, v_mean, attn_bf);

    out_gemm_kernel<<<dim3(EMB / 64, NROWS / 64), dim3(256), 0, stream>>>(
        attn_bf, WoT, bo, out);
}